// Round 1
// baseline (639.405 us; speedup 1.0000x reference)
//
#include <hip/hip_runtime.h>

#define NN 10000
#define DF 128
#define NE 640000

// ---------------------------------------------------------------------------
// K1: Xs = feat @ W_src^T + b_src        [NN x 128]
// W_src is [out=128][in=128] row-major (torch Linear layout).
// LDS holds W transposed: Wt[k*129 + c] = W_src[c][k]  (pad 129 -> no bank conflicts)
// 512 threads = 8 waves, one row per wave.
// ---------------------------------------------------------------------------
__global__ __launch_bounds__(512) void xform_src(const float* __restrict__ feat,
                                                 const float* __restrict__ W,
                                                 const float* __restrict__ b,
                                                 float* __restrict__ Xs, int n)
{
    __shared__ float Wt[128 * 129];
    const int tid = threadIdx.x;
    for (int i = tid; i < 128 * 128; i += 512) {
        int c = i >> 7, k = i & 127;
        Wt[k * 129 + c] = W[i];
    }
    __syncthreads();

    const int wave = tid >> 6, lane = tid & 63;
    const int row = blockIdx.x * 8 + wave;
    if (row >= n) return;

    const int c0 = lane, c1 = lane + 64;
    float acc0 = b[c0], acc1 = b[c1];
    const float4* frow = (const float4*)(feat + (size_t)row * DF);
#pragma unroll
    for (int k4 = 0; k4 < 32; ++k4) {
        float4 f = frow[k4];
        int k = k4 * 4;
        acc0 += f.x * Wt[(k + 0) * 129 + c0]; acc1 += f.x * Wt[(k + 0) * 129 + c1];
        acc0 += f.y * Wt[(k + 1) * 129 + c0]; acc1 += f.y * Wt[(k + 1) * 129 + c1];
        acc0 += f.z * Wt[(k + 2) * 129 + c0]; acc1 += f.z * Wt[(k + 2) * 129 + c1];
        acc0 += f.w * Wt[(k + 3) * 129 + c0]; acc1 += f.w * Wt[(k + 3) * 129 + c1];
    }
    Xs[(size_t)row * DF + c0] = acc0;
    Xs[(size_t)row * DF + c1] = acc1;
}

// ---------------------------------------------------------------------------
// K2: scatter-add Xs[src[e]] into agg[dst[e]], count degrees.
// One wave per edge; lane handles 2 consecutive features (float2 = 8B/lane,
// 512B/edge fully coalesced). Native fp32 atomics (unsafeAtomicAdd ->
// global_atomic_add_f32 on gfx950).
// ---------------------------------------------------------------------------
__global__ __launch_bounds__(256) void scatter_edges(const float* __restrict__ Xs,
                                                     const int* __restrict__ src,
                                                     const int* __restrict__ dst,
                                                     float* __restrict__ agg,
                                                     float* __restrict__ deg, int nE)
{
    const int t = blockIdx.x * 256 + threadIdx.x;
    const int e = t >> 6, lane = t & 63;
    if (e >= nE) return;
    const int s = src[e], d = dst[e];
    const float2 v = *(const float2*)(Xs + (size_t)s * DF + lane * 2);
    float* ap = agg + (size_t)d * DF + lane * 2;
    unsafeAtomicAdd(ap, v.x);
    unsafeAtomicAdd(ap + 1, v.y);
    if (lane == 0) unsafeAtomicAdd(deg + d, 1.0f);
}

// ---------------------------------------------------------------------------
// K3: out = feat @ Wfc[:, :128]^T + (agg/max(deg,1)) @ Wfc[:, 128:]^T + b_fc
// W_fc is [out=128][in=256] row-major. LDS: Wt[j*129 + o] = W_fc[o][j]
// (j = 0..255, 132KB LDS). 512 threads = 8 waves, one row per wave.
// ---------------------------------------------------------------------------
__global__ __launch_bounds__(512) void apply_fc(const float* __restrict__ feat,
                                                const float* __restrict__ agg,
                                                const float* __restrict__ deg,
                                                const float* __restrict__ Wfc,
                                                const float* __restrict__ bfc,
                                                float* __restrict__ out, int n)
{
    __shared__ float Wt[256 * 129];
    const int tid = threadIdx.x;
    for (int i = tid; i < 256 * 128; i += 512) {
        int o = i >> 8, j = i & 255;
        Wt[j * 129 + o] = Wfc[i];
    }
    __syncthreads();

    const int wave = tid >> 6, lane = tid & 63;
    const int row = blockIdx.x * 8 + wave;
    if (row >= n) return;

    const float inv = 1.0f / fmaxf(deg[row], 1.0f);
    const int o0 = lane, o1 = lane + 64;
    float acc0 = bfc[o0], acc1 = bfc[o1];

    const float4* frow = (const float4*)(feat + (size_t)row * DF);
#pragma unroll
    for (int k4 = 0; k4 < 32; ++k4) {
        float4 f = frow[k4];
        int j = k4 * 4;
        acc0 += f.x * Wt[(j + 0) * 129 + o0]; acc1 += f.x * Wt[(j + 0) * 129 + o1];
        acc0 += f.y * Wt[(j + 1) * 129 + o0]; acc1 += f.y * Wt[(j + 1) * 129 + o1];
        acc0 += f.z * Wt[(j + 2) * 129 + o0]; acc1 += f.z * Wt[(j + 2) * 129 + o1];
        acc0 += f.w * Wt[(j + 3) * 129 + o0]; acc1 += f.w * Wt[(j + 3) * 129 + o1];
    }
    const float4* arow = (const float4*)(agg + (size_t)row * DF);
#pragma unroll
    for (int k4 = 0; k4 < 32; ++k4) {
        float4 a = arow[k4];
        int j = 128 + k4 * 4;
        float ax = a.x * inv, ay = a.y * inv, az = a.z * inv, aw = a.w * inv;
        acc0 += ax * Wt[(j + 0) * 129 + o0]; acc1 += ax * Wt[(j + 0) * 129 + o1];
        acc0 += ay * Wt[(j + 1) * 129 + o0]; acc1 += ay * Wt[(j + 1) * 129 + o1];
        acc0 += az * Wt[(j + 2) * 129 + o0]; acc1 += az * Wt[(j + 2) * 129 + o1];
        acc0 += aw * Wt[(j + 3) * 129 + o0]; acc1 += aw * Wt[(j + 3) * 129 + o1];
    }
    out[(size_t)row * DF + o0] = acc0;
    out[(size_t)row * DF + o1] = acc1;
}

extern "C" void kernel_launch(void* const* d_in, const int* in_sizes, int n_in,
                              void* d_out, int out_size, void* d_ws, size_t ws_size,
                              hipStream_t stream) {
    const float* feat  = (const float*)d_in[0];   // [NN, 128]
    const float* W_src = (const float*)d_in[1];   // [128, 128]
    const float* b_src = (const float*)d_in[2];   // [128]
    const float* W_fc  = (const float*)d_in[3];   // [128, 256]
    const float* b_fc  = (const float*)d_in[4];   // [128]
    const int*   src   = (const int*)d_in[5];     // [NE]
    const int*   dst   = (const int*)d_in[6];     // [NE]
    float* out = (float*)d_out;

    // workspace layout: agg [NN*128] | deg [NN] | Xs [NN*128]
    float* agg = (float*)d_ws;
    float* deg = agg + (size_t)NN * DF;
    float* Xs  = deg + NN;

    // zero agg + deg (needed every call; harness does not re-poison)
    hipMemsetAsync(d_ws, 0, ((size_t)NN * DF + NN) * sizeof(float), stream);

    xform_src<<<(NN + 7) / 8, 512, 0, stream>>>(feat, W_src, b_src, Xs, NN);
    scatter_edges<<<(NE * 64 + 255) / 256, 256, 0, stream>>>(Xs, src, dst, agg, deg, NE);
    apply_fc<<<(NN + 7) / 8, 512, 0, stream>>>(feat, agg, deg, W_fc, b_fc, out, NN);
}

// Round 2
// 196.623 us; speedup vs baseline: 3.2519x; 3.2519x over previous
//
#include <hip/hip_runtime.h>

#define NN 10000
#define DF 128
#define NE 640000

// ---------------------------------------------------------------------------
// K1: Xs = feat @ W_src^T + b_src        [NN x 128]
// Wt in LDS transposed with +1 pad (stride 129, conflict-free).
// 512 threads = 8 waves, one row per wave, 2 output cols per lane.
// ---------------------------------------------------------------------------
__global__ __launch_bounds__(512) void xform_src(const float* __restrict__ feat,
                                                 const float* __restrict__ W,
                                                 const float* __restrict__ b,
                                                 float* __restrict__ Xs, int n)
{
    __shared__ float Wt[128 * 129];
    const int tid = threadIdx.x;
    for (int i = tid; i < 128 * 128; i += 512) {
        int c = i >> 7, k = i & 127;
        Wt[k * 129 + c] = W[i];
    }
    __syncthreads();

    const int wave = tid >> 6, lane = tid & 63;
    const int row = blockIdx.x * 8 + wave;
    if (row >= n) return;

    const int c0 = lane, c1 = lane + 64;
    float acc0 = b[c0], acc1 = b[c1];
    const float4* frow = (const float4*)(feat + (size_t)row * DF);
#pragma unroll
    for (int k4 = 0; k4 < 32; ++k4) {
        float4 f = frow[k4];
        int k = k4 * 4;
        acc0 += f.x * Wt[(k + 0) * 129 + c0]; acc1 += f.x * Wt[(k + 0) * 129 + c1];
        acc0 += f.y * Wt[(k + 1) * 129 + c0]; acc1 += f.y * Wt[(k + 1) * 129 + c1];
        acc0 += f.z * Wt[(k + 2) * 129 + c0]; acc1 += f.z * Wt[(k + 2) * 129 + c1];
        acc0 += f.w * Wt[(k + 3) * 129 + c0]; acc1 += f.w * Wt[(k + 3) * 129 + c1];
    }
    Xs[(size_t)row * DF + c0] = acc0;
    Xs[(size_t)row * DF + c1] = acc1;
}

// ---------------------------------------------------------------------------
// K2a: in-degree histogram (int atomics — native, fast)
// ---------------------------------------------------------------------------
__global__ __launch_bounds__(256) void hist_deg(const int* __restrict__ dst,
                                                int* __restrict__ cnt, int nE)
{
    const int e = blockIdx.x * 256 + threadIdx.x;
    if (e < nE) atomicAdd(&cnt[dst[e]], 1);
}

// ---------------------------------------------------------------------------
// K2b: exclusive scan of cnt[0..NN) -> off[0..NN]. Single 1024-thread block;
// each thread serially sums 10 elements, then Hillis-Steele block scan.
// ---------------------------------------------------------------------------
__global__ __launch_bounds__(1024) void scan_offsets(const int* __restrict__ cnt,
                                                     int* __restrict__ off)
{
    __shared__ int part[1024];
    const int t = threadIdx.x;
    const int base = t * 10;
    int local[10];
    int s = 0;
    for (int i = 0; i < 10; ++i) {
        int idx = base + i;
        int c = (idx < NN) ? cnt[idx] : 0;
        local[i] = s;
        s += c;
    }
    part[t] = s;
    __syncthreads();
    for (int d = 1; d < 1024; d <<= 1) {
        int v = (t >= d) ? part[t - d] : 0;
        __syncthreads();
        part[t] += v;
        __syncthreads();
    }
    const int pre = (t == 0) ? 0 : part[t - 1];
    for (int i = 0; i < 10; ++i) {
        int idx = base + i;
        if (idx < NN) off[idx] = pre + local[i];
    }
    if (t == 1023) off[NN] = part[1023];
}

// ---------------------------------------------------------------------------
// K2c: scatter src node ids into CSR buckets.
// ---------------------------------------------------------------------------
__global__ __launch_bounds__(256) void scatter_idx(const int* __restrict__ src,
                                                   const int* __restrict__ dst,
                                                   const int* __restrict__ off,
                                                   int* __restrict__ cursor,
                                                   int* __restrict__ srcs, int nE)
{
    const int e = blockIdx.x * 256 + threadIdx.x;
    if (e < nE) {
        const int d = dst[e];
        const int p = atomicAdd(&cursor[d], 1);
        srcs[off[d] + p] = src[e];
    }
}

// ---------------------------------------------------------------------------
// K3: neigh[v] = mean over in-edges of Xs[src]. One wave per node, lane owns
// 2 features (float2 -> the wave reads the full 512B row coalesced).
// Index loads are wave-uniform (one request, broadcast). No fp atomics.
// ---------------------------------------------------------------------------
__global__ __launch_bounds__(256) void gather_mean(const float* __restrict__ Xs,
                                                   const int* __restrict__ srcs,
                                                   const int* __restrict__ off,
                                                   float* __restrict__ neigh, int n)
{
    const int wave = threadIdx.x >> 6, lane = threadIdx.x & 63;
    const int v = blockIdx.x * 4 + wave;
    if (v >= n) return;
    const int s0 = off[v], s1 = off[v + 1];
    const int cnt = s1 - s0;

    float ax = 0.f, ay = 0.f;
    int i = s0;
    for (; i + 4 <= s1; i += 4) {
        const int ia = srcs[i + 0];
        const int ib = srcs[i + 1];
        const int ic = srcs[i + 2];
        const int id = srcs[i + 3];
        const float2 a = *(const float2*)(Xs + (size_t)ia * DF + lane * 2);
        const float2 b = *(const float2*)(Xs + (size_t)ib * DF + lane * 2);
        const float2 c = *(const float2*)(Xs + (size_t)ic * DF + lane * 2);
        const float2 d = *(const float2*)(Xs + (size_t)id * DF + lane * 2);
        ax += (a.x + b.x) + (c.x + d.x);
        ay += (a.y + b.y) + (c.y + d.y);
    }
    for (; i < s1; ++i) {
        const int s = srcs[i];
        const float2 a = *(const float2*)(Xs + (size_t)s * DF + lane * 2);
        ax += a.x; ay += a.y;
    }
    const float inv = (cnt > 0) ? (1.0f / (float)cnt) : 0.0f;
    float2 o; o.x = ax * inv; o.y = ay * inv;
    *(float2*)(neigh + (size_t)v * DF + lane * 2) = o;
}

// ---------------------------------------------------------------------------
// K4: out = feat @ Wfc[:, :128]^T + neigh @ Wfc[:, 128:]^T + b_fc
// W_fc [128][256] row-major, transposed into padded LDS (132 KB).
// ---------------------------------------------------------------------------
__global__ __launch_bounds__(512) void apply_fc(const float* __restrict__ feat,
                                                const float* __restrict__ neigh,
                                                const float* __restrict__ Wfc,
                                                const float* __restrict__ bfc,
                                                float* __restrict__ out, int n)
{
    __shared__ float Wt[256 * 129];
    const int tid = threadIdx.x;
    for (int i = tid; i < 256 * 128; i += 512) {
        int o = i >> 8, j = i & 255;
        Wt[j * 129 + o] = Wfc[i];
    }
    __syncthreads();

    const int wave = tid >> 6, lane = tid & 63;
    const int row = blockIdx.x * 8 + wave;
    if (row >= n) return;

    const int o0 = lane, o1 = lane + 64;
    float acc0 = bfc[o0], acc1 = bfc[o1];

    const float4* frow = (const float4*)(feat + (size_t)row * DF);
#pragma unroll
    for (int k4 = 0; k4 < 32; ++k4) {
        float4 f = frow[k4];
        int j = k4 * 4;
        acc0 += f.x * Wt[(j + 0) * 129 + o0]; acc1 += f.x * Wt[(j + 0) * 129 + o1];
        acc0 += f.y * Wt[(j + 1) * 129 + o0]; acc1 += f.y * Wt[(j + 1) * 129 + o1];
        acc0 += f.z * Wt[(j + 2) * 129 + o0]; acc1 += f.z * Wt[(j + 2) * 129 + o1];
        acc0 += f.w * Wt[(j + 3) * 129 + o0]; acc1 += f.w * Wt[(j + 3) * 129 + o1];
    }
    const float4* arow = (const float4*)(neigh + (size_t)row * DF);
#pragma unroll
    for (int k4 = 0; k4 < 32; ++k4) {
        float4 a = arow[k4];
        int j = 128 + k4 * 4;
        acc0 += a.x * Wt[(j + 0) * 129 + o0]; acc1 += a.x * Wt[(j + 0) * 129 + o1];
        acc0 += a.y * Wt[(j + 1) * 129 + o0]; acc1 += a.y * Wt[(j + 1) * 129 + o1];
        acc0 += a.z * Wt[(j + 2) * 129 + o0]; acc1 += a.z * Wt[(j + 2) * 129 + o1];
        acc0 += a.w * Wt[(j + 3) * 129 + o0]; acc1 += a.w * Wt[(j + 3) * 129 + o1];
    }
    out[(size_t)row * DF + o0] = acc0;
    out[(size_t)row * DF + o1] = acc1;
}

extern "C" void kernel_launch(void* const* d_in, const int* in_sizes, int n_in,
                              void* d_out, int out_size, void* d_ws, size_t ws_size,
                              hipStream_t stream) {
    const float* feat  = (const float*)d_in[0];   // [NN, 128]
    const float* W_src = (const float*)d_in[1];   // [128, 128]
    const float* b_src = (const float*)d_in[2];   // [128]
    const float* W_fc  = (const float*)d_in[3];   // [128, 256]
    const float* b_fc  = (const float*)d_in[4];   // [128]
    const int*   src   = (const int*)d_in[5];     // [NE]
    const int*   dst   = (const int*)d_in[6];     // [NE]
    float* out = (float*)d_out;

    // workspace layout (floats then ints):
    // Xs [NN*DF] | neigh [NN*DF] | cnt [NN] | cursor [NN] | off [NN+1] | srcs [NE]
    float* Xs    = (float*)d_ws;
    float* neigh = Xs + (size_t)NN * DF;
    int*   cnt    = (int*)(neigh + (size_t)NN * DF);
    int*   cursor = cnt + NN;
    int*   off    = cursor + NN;
    int*   srcs   = off + (NN + 1);

    // zero cnt + cursor only (80 KB)
    hipMemsetAsync(cnt, 0, 2 * NN * sizeof(int), stream);

    xform_src  <<<(NN + 7) / 8, 512, 0, stream>>>(feat, W_src, b_src, Xs, NN);
    hist_deg   <<<(NE + 255) / 256, 256, 0, stream>>>(dst, cnt, NE);
    scan_offsets<<<1, 1024, 0, stream>>>(cnt, off);
    scatter_idx<<<(NE + 255) / 256, 256, 0, stream>>>(src, dst, off, cursor, srcs, NE);
    gather_mean<<<(NN + 3) / 4, 256, 0, stream>>>(Xs, srcs, off, neigh, NN);
    apply_fc   <<<(NN + 7) / 8, 512, 0, stream>>>(feat, neigh, W_fc, b_fc, out, NN);
}